// Round 1
// 214.033 us; speedup vs baseline: 1.0381x; 1.0381x over previous
//
#include <hip/hip_runtime.h>

// Forward kinematics for a serial revolute chain.
// q: [B, L] fp32, axes: [L,3], t_fix: [L,3]  ->  out: [B, L, 4, 4] fp32.
// qd is unused by the reference output.
//
// 4 lanes per batch element, one OUTPUT ROW each (row i of R_parent@J
// depends only on row i of R_parent). Rows are stored DIRECTLY to global:
// for each link, a 4-lane group writes 64B contiguous; consecutive links
// from the same group fill adjacent 64B halves of the same 128B L2 lines
// back-to-back, so L2 write-combining emits full-line HBM writebacks.
//
// Rationale vs the previous (221 us) version: the 50KB LDS staging tile
// bought 1KB-contiguous drain stores but capped residency at 3 blocks/CU
// (1.5 waves/SIMD). Effective BW was ~0.96 TB/s vs the 6.5 TB/s the
// harness's fill kernels demonstrate -- latency-bound, not BW-bound.
// Dropping the tile trades store granularity (64B chunks, L2-merged)
// for 4-5x more waves in flight.

typedef float v4 __attribute__((ext_vector_type(4)));

constexpr int L = 24;

__global__ __launch_bounds__(256, 4) void fk_kernel(
    const float* __restrict__ q,
    const float* __restrict__ axes,
    const float* __restrict__ tfix,
    float* __restrict__ out,
    int nb)
{
    // 12 precomputed floats per link, packed so the unrolled loop reads
    // them as 3x ds_read_b128 (lane-uniform -> bank broadcast):
    // {ax,ay,az,tx, ty,tz,xx,yy, zz,xy,xz,yz}
    __shared__ float s_lnk[L][12];

    if (threadIdx.x < L) {
        const int l = threadIdx.x;
        float ax = axes[l * 3 + 0], ay = axes[l * 3 + 1], az = axes[l * 3 + 2];
        float inv = rsqrtf(ax * ax + ay * ay + az * az);
        ax *= inv; ay *= inv; az *= inv;
        s_lnk[l][0] = ax;             s_lnk[l][1] = ay;             s_lnk[l][2] = az;
        s_lnk[l][3] = tfix[l * 3 + 0]; s_lnk[l][4] = tfix[l * 3 + 1]; s_lnk[l][5] = tfix[l * 3 + 2];
        s_lnk[l][6] = ax * ax;        s_lnk[l][7] = ay * ay;
        s_lnk[l][8] = az * az;        s_lnk[l][9] = ax * ay;
        s_lnk[l][10] = ax * az;       s_lnk[l][11] = ay * az;
    }
    __syncthreads();

    const int tid = blockIdx.x * 256 + threadIdx.x;
    const int b = tid >> 2;   // batch element
    const int r = tid & 3;    // output row owned by this lane
    if (b >= nb) return;

    // Load this element's 24 joint angles (redundant across the 4-lane
    // group; L1 broadcast absorbs it).
    float qv[L];
    {
        const v4* q4 = (const v4*)(q + (size_t)b * L);
        #pragma unroll
        for (int i = 0; i < L / 4; ++i) {
            v4 v = q4[i];
            qv[4 * i + 0] = v.x;
            qv[4 * i + 1] = v.y;
            qv[4 * i + 2] = v.z;
            qv[4 * i + 3] = v.w;
        }
    }

    // Row r of the identity pose; row 3 -> (0,0,0,1) and stays that way
    // (Ra=Rb=Rc=0 so the recurrence below is a fixed point).
    float Ra = (r == 0) ? 1.f : 0.f;
    float Rb = (r == 1) ? 1.f : 0.f;
    float Rc = (r == 2) ? 1.f : 0.f;
    float t  = (r == 3) ? 1.f : 0.f;

    v4* orow = (v4*)out + (size_t)b * (4 * L) + r;   // + l*4 per link

    #pragma unroll
    for (int l = 0; l < L; ++l) {
        const float ax = s_lnk[l][0], ay = s_lnk[l][1], az = s_lnk[l][2];
        const float fx = s_lnk[l][3], fy = s_lnk[l][4], fz = s_lnk[l][5];
        const float xx = s_lnk[l][6], yy = s_lnk[l][7], zz = s_lnk[l][8];
        const float xy = s_lnk[l][9], xz = s_lnk[l][10], yz = s_lnk[l][11];

        float s, c;
        __sincosf(qv[l], &s, &c);
        const float omc = 1.0f - c;

        // Rodrigues for unit axis a: J = c*I + s*K + (1-c) a a^T
        const float J00 = fmaf(omc, xx, c);
        const float J11 = fmaf(omc, yy, c);
        const float J22 = fmaf(omc, zz, c);
        const float oxy = omc * xy, oxz = omc * xz, oyz = omc * yz;
        const float sx = s * ax, sy = s * ay, sz = s * az;
        const float J01 = oxy - sz, J10 = oxy + sz;
        const float J02 = oxz + sy, J20 = oxz - sy;
        const float J12 = oyz - sx, J21 = oyz + sx;

        // translation uses the PARENT rotation row (pre-update)
        t = fmaf(Ra, fx, fmaf(Rb, fy, fmaf(Rc, fz, t)));

        // row r of R_child = row r of R_parent @ J
        const float na  = fmaf(Ra, J00, fmaf(Rb, J10, Rc * J20));
        const float nb_ = fmaf(Ra, J01, fmaf(Rb, J11, Rc * J21));
        const float nc  = fmaf(Ra, J02, fmaf(Rb, J12, Rc * J22));
        Ra = na; Rb = nb_; Rc = nc;

        // 4-lane group writes 64B contiguous at out[b][l][r][0..3].
        orow[l * 4] = v4{Ra, Rb, Rc, t};
    }
}

extern "C" void kernel_launch(void* const* d_in, const int* in_sizes, int n_in,
                              void* d_out, int out_size, void* d_ws, size_t ws_size,
                              hipStream_t stream) {
    const float* q    = (const float*)d_in[0];
    // d_in[1] = qd: unused by the reference output
    const float* axes = (const float*)d_in[2];
    const float* tfix = (const float*)d_in[3];
    float* out = (float*)d_out;

    const int nb = in_sizes[0] / L;                 // 131072
    const long long nthreads = (long long)nb * 4;   // 4 lanes per element
    const int grid = (int)((nthreads + 255) / 256);
    fk_kernel<<<grid, 256, 0, stream>>>(q, axes, tfix, out, nb);
}